// Round 1
// baseline (235.566 us; speedup 1.0000x reference)
//
#include <hip/hip_runtime.h>
#include <hip/hip_bf16.h>

typedef float f32x4 __attribute__((ext_vector_type(4)));
typedef short s16x8 __attribute__((ext_vector_type(8)));

using bf16 = __hip_bfloat16;

namespace {
constexpr int KD = 1024;   // 8 * C_IN
constexpr int BM = 128;
constexpr int BK = 32;
constexpr int NT = KD / BK;   // 32 K-tiles
}

// XOR swizzle over 16B chunks: row stride = 4 chunks (64B). Spread the 8-row
// bank-alias pattern bijectively: slot = (row ^ bit2(row))*4 + (chunk ^ (row&3)).
__device__ __forceinline__ int swz_slot(int row, int c) {
  return (row ^ ((row >> 2) & 1)) * 4 + (c ^ (row & 3));
}
// inverse: which (row, chunk) data must be placed at linear slot s
__device__ __forceinline__ void swz_inv(int s, int& row, int& c) {
  int rp = s >> 2, x = s & 3;
  row = rp ^ ((rp >> 2) & 1);   // bit2 unchanged by the bit0 XOR
  c = x ^ (row & 3);
}

__device__ __forceinline__ s16x8 cvt8(f32x4 a, f32x4 b) {
  union { s16x8 v; bf16 h[8]; } u;
#pragma unroll
  for (int j = 0; j < 4; ++j) u.h[j] = __float2bfloat16(a[j]);
#pragma unroll
  for (int j = 0; j < 4; ++j) u.h[j + 4] = __float2bfloat16(b[j]);
  return u.v;
}

// weights [1024][256] fp32 -> Bt [256][1024] bf16 (transposed, MFMA-B friendly)
__global__ void k_transpose_w(const float* __restrict__ w, bf16* __restrict__ bt) {
  int t = blockIdx.x * 256 + threadIdx.x;   // 32768 threads
  int n = t & 255;
  int k0 = (t >> 8) << 3;
  union { s16x8 v; bf16 h[8]; } u;
#pragma unroll
  for (int j = 0; j < 8; ++j)
    u.h[j] = __float2bfloat16(w[(size_t)(k0 + j) * 256 + n]);
  *(s16x8*)(bt + (size_t)n * KD + k0) = u.v;
}

__global__ void k_clear_flags(int* __restrict__ flags, int np4) {
  int i = blockIdx.x * 256 + threadIdx.x;
  if (i < np4) ((int4*)flags)[i] = make_int4(0, 0, 0, 0);
}

__global__ void k_set_flags(const int* __restrict__ idx, int* __restrict__ flags, int m) {
  int i = blockIdx.x * 256 + threadIdx.x;
  if (i < m) flags[idx[i]] = 1;
}

// zero only the empty parent rows (saves 128 MB of writes vs full memset)
__global__ void k_zero_empty(const int* __restrict__ flags, float* __restrict__ out) {
  int row = blockIdx.x * 4 + (threadIdx.x >> 6);
  int lane = threadIdx.x & 63;
  if (flags[row] == 0) {
    f32x4 z = {0.f, 0.f, 0.f, 0.f};
    *(f32x4*)(out + (size_t)row * 256 + lane * 4) = z;
  }
}

// GEMM: C[idx[m], n] = sum_k A[m,k] * B[k,n]; A fp32 (cast->bf16 on stage),
// Bt bf16 pre-transposed [n][k]. BM=128 x BN=256(full) x BK=32, 8 waves.
__global__ __launch_bounds__(512, 4)
void k_gemm(const float* __restrict__ A, const bf16* __restrict__ Bt,
            const int* __restrict__ idx, float* __restrict__ out) {
  __shared__ bf16 As[2][BM * BK];   // 2 x 8 KB
  __shared__ bf16 Bs[2][256 * BK];  // 2 x 16 KB

  const int tid = threadIdx.x;
  const int lane = tid & 63;
  const int wave = tid >> 6;   // 0..7
  const int wm = wave >> 2;    // 0..1  (row half)
  const int wn = wave & 3;     // 0..3  (col quarter)
  const int m0 = blockIdx.x * BM;

  // ---- staging coordinates ----
  // A: thread covers (row ar, chunk ac) = 8 consecutive fp32
  const int ar = tid >> 2;
  const int ac = tid & 3;
  const float* aptr = A + (size_t)(m0 + ar) * KD + ac * 8;
  const int a_w_off = swz_slot(ar, ac) * 8;

  // B: thread covers linear slots tid and 512+tid (writes conflict-free);
  // source address carries the inverse swizzle.
  int bn0, bc0, bn1, bc1;
  swz_inv(tid, bn0, bc0);
  swz_inv(512 + tid, bn1, bc1);
  const bf16* bp0 = Bt + (size_t)bn0 * KD + bc0 * 8;
  const bf16* bp1 = Bt + (size_t)bn1 * KD + bc1 * 8;
  const int b_w_off0 = tid * 8;
  const int b_w_off1 = (512 + tid) * 8;

  // ---- fragment read offsets (16x16x32: lane holds row l&15, k-octet l>>4) ----
  const int arow = wm * 64 + (lane & 15);
  const int kc = lane >> 4;
  const int a_r_off = swz_slot(arow, kc) * 8;   // + fm*512
  const int brow = wn * 64 + (lane & 15);
  const int b_r_off = swz_slot(brow, kc) * 8;   // + fn*512

  f32x4 acc[4][4] = {};

  // ---- prologue: stage tile 0 ----
  {
    f32x4 a0 = *(const f32x4*)aptr;
    f32x4 a1 = *(const f32x4*)(aptr + 4);
    s16x8 b0 = *(const s16x8*)bp0;
    s16x8 b1 = *(const s16x8*)bp1;
    *(s16x8*)(&As[0][a_w_off]) = cvt8(a0, a1);
    *(s16x8*)(&Bs[0][b_w_off0]) = b0;
    *(s16x8*)(&Bs[0][b_w_off1]) = b1;
  }
  __syncthreads();

  int cur = 0;
#pragma unroll 1
  for (int t = 0; t < NT; ++t) {
    f32x4 na0, na1;
    s16x8 nb0, nb1;
    const bool pf = (t + 1 < NT);
    if (pf) {  // issue next-tile loads early; compute hides latency
      const float* ap = aptr + (t + 1) * BK;
      na0 = *(const f32x4*)ap;
      na1 = *(const f32x4*)(ap + 4);
      nb0 = *(const s16x8*)(bp0 + (t + 1) * BK);
      nb1 = *(const s16x8*)(bp1 + (t + 1) * BK);
    }

    s16x8 af[4], bfr[4];
#pragma unroll
    for (int fm = 0; fm < 4; ++fm)
      af[fm] = *(const s16x8*)(&As[cur][a_r_off + fm * 512]);
#pragma unroll
    for (int fn = 0; fn < 4; ++fn)
      bfr[fn] = *(const s16x8*)(&Bs[cur][b_r_off + fn * 512]);

#pragma unroll
    for (int fm = 0; fm < 4; ++fm)
#pragma unroll
      for (int fn = 0; fn < 4; ++fn)
        acc[fm][fn] = __builtin_amdgcn_mfma_f32_16x16x32_bf16(
            af[fm], bfr[fn], acc[fm][fn], 0, 0, 0);

    if (pf) {
      int nxt = cur ^ 1;
      *(s16x8*)(&As[nxt][a_w_off]) = cvt8(na0, na1);
      *(s16x8*)(&Bs[nxt][b_w_off0]) = nb0;
      *(s16x8*)(&Bs[nxt][b_w_off1]) = nb1;
      cur = nxt;
    }
    __syncthreads();
  }

  // ---- epilogue: C/D layout col = lane&15, row = (lane>>4)*4 + j ----
  const int col0 = wn * 64 + (lane & 15);
  const int rb = m0 + wm * 64 + ((lane >> 4) << 2);
#pragma unroll
  for (int fm = 0; fm < 4; ++fm) {
#pragma unroll
    for (int j = 0; j < 4; ++j) {
      int orow = idx[rb + fm * 16 + j];
      float* op = out + (size_t)orow * 256 + col0;
#pragma unroll
      for (int fn = 0; fn < 4; ++fn)
        op[fn * 16] = acc[fm][fn][j];
    }
  }
}

extern "C" void kernel_launch(void* const* d_in, const int* in_sizes, int n_in,
                              void* d_out, int out_size, void* d_ws, size_t ws_size,
                              hipStream_t stream) {
  const float* data = (const float*)d_in[0];   // [N, 128] == [M, 1024]
  const float* w    = (const float*)d_in[1];   // [8,128,256] == [1024, 256]
  const int*   idx  = (const int*)d_in[2];     // [M] sorted unique parent slots
  float* out = (float*)d_out;                  // [NP, 256]

  const int M  = in_sizes[2];        // 131072
  const int NP = out_size / 256;     // 262144

  int* flags = (int*)d_ws;                                   // NP ints (1 MB)
  bf16* bt = (bf16*)((char*)d_ws + (size_t)NP * sizeof(int)); // 512 KB

  k_transpose_w<<<128, 256, 0, stream>>>(w, bt);
  k_clear_flags<<<(NP / 4 + 255) / 256, 256, 0, stream>>>(flags, NP / 4);
  k_set_flags<<<(M + 255) / 256, 256, 0, stream>>>(idx, flags, M);
  k_zero_empty<<<NP / 4, 256, 0, stream>>>(flags, out);
  k_gemm<<<M / BM, 512, 0, stream>>>(data, bt, idx, out);
}